// Round 5
// baseline (197.443 us; speedup 1.0000x reference)
//
#include <hip/hip_runtime.h>

// Geometry fixed by the reference: x [B=2, C=64, R_rot=6, charts=5, H=128, W=256] fp32.
#define RROT   6
#define CHARTS 5
#define CHART_STRIDE 32768LL                 // H*W = 128*256
#define ROT_STRIDE   163840LL                // 5*CHART_STRIDE
#define BC_STRIDE    983040LL                // 6*ROT_STRIDE

typedef float f4 __attribute__((ext_vector_type(4)));

// A chart = 8192 granules = 8 steps of 1024. Pole granules are chart-offsets
// 0 (pole1, col 0) and 32 (pole2, col 128): they occur only in steps with
// s%8==0, held by threads 0 and 32 in their FIRST load. This fixes v.x for
// exactly those (step, thread) pairs, reading the 6-rot x 5-neighbor mean
// straight from the input (neighbors never touch pole positions).
__device__ __forceinline__ void fix_pole(long long s, int t, f4& v,
                                         const float* __restrict__ x) {
    if (((s & 7) != 0) | ((t != 0) & (t != 32))) return;
    long long chart_g = s >> 3;            // = (bc*6 + r)*5 + c
    int c  = (int)(chart_g % CHARTS);
    long long bc = chart_g / (CHARTS * RROT);
    int cm = (c + CHARTS - 1) % CHARTS;
    const float* base = x + bc * BC_STRIDE;
    float acc = 0.0f;
    if (t == 0) {
        // V1 of pole (0,0): [c,1,0],[c,1,1],[c,0,1],[cm,127,128],[cm,127,127]
        #pragma unroll
        for (int r = 0; r < RROT; ++r) {
            const float* rb = base + r * ROT_STRIDE;
            acc += rb[c  * CHART_STRIDE + 256]
                 + rb[c  * CHART_STRIDE + 257]
                 + rb[c  * CHART_STRIDE + 1]
                 + rb[cm * CHART_STRIDE + 32640]
                 + rb[cm * CHART_STRIDE + 32639];
        }
    } else {
        // V2 of pole (0,128): [c,1,128],[c,1,129],[c,0,129],[cm,127,255],[c,0,127]
        #pragma unroll
        for (int r = 0; r < RROT; ++r) {
            const float* rb = base + r * ROT_STRIDE;
            acc += rb[c  * CHART_STRIDE + 384]
                 + rb[c  * CHART_STRIDE + 385]
                 + rb[c  * CHART_STRIDE + 129]
                 + rb[cm * CHART_STRIDE + 32767]
                 + rb[c  * CHART_STRIDE + 127];
        }
    }
    v.x = acc * (1.0f / 30.0f);
}

// Hand-pipelined streaming copy with inline pole fix. Each block owns
// steps_pb CONTIGUOUS steps of 1024 granules (16 KB); next step's 4 loads
// issue before current step's 4 stores (8 loads in flight at steady state).
__global__ __launch_bounds__(256) void smooth_copy(
        const f4* __restrict__ in, f4* __restrict__ out,
        long long n4, long long steps_pb, const float* __restrict__ x) {
    const int t = threadIdx.x;
    const long long n_steps = n4 >> 10;
    long long s = (long long)blockIdx.x * steps_pb;
    long long s_end = s + steps_pb;
    if (s_end > n_steps) s_end = n_steps;
    if (s < s_end) {
        long long b = (s << 10) + t;
        f4 a0 = __builtin_nontemporal_load(&in[b]);
        f4 a1 = __builtin_nontemporal_load(&in[b + 256]);
        f4 a2 = __builtin_nontemporal_load(&in[b + 512]);
        f4 a3 = __builtin_nontemporal_load(&in[b + 768]);
        fix_pole(s, t, a0, x);
        for (;;) {
            long long s2 = s + 1;
            if (s2 < s_end) {
                long long b2 = b + 1024;
                f4 c0 = __builtin_nontemporal_load(&in[b2]);
                f4 c1 = __builtin_nontemporal_load(&in[b2 + 256]);
                f4 c2 = __builtin_nontemporal_load(&in[b2 + 512]);
                f4 c3 = __builtin_nontemporal_load(&in[b2 + 768]);
                fix_pole(s2, t, c0, x);
                __builtin_nontemporal_store(a0, &out[b]);
                __builtin_nontemporal_store(a1, &out[b + 256]);
                __builtin_nontemporal_store(a2, &out[b + 512]);
                __builtin_nontemporal_store(a3, &out[b + 768]);
                a0 = c0; a1 = c1; a2 = c2; a3 = c3;
                s = s2; b = b2;
            } else {
                __builtin_nontemporal_store(a0, &out[b]);
                __builtin_nontemporal_store(a1, &out[b + 256]);
                __builtin_nontemporal_store(a2, &out[b + 512]);
                __builtin_nontemporal_store(a3, &out[b + 768]);
                break;
            }
        }
    }
    // Tail (n4 % 1024) — empty for this shape, kept for safety. Pole granules
    // can never land here (they sit at chart starts, multiples of 8192).
    long long tail = n_steps << 10;
    long long stride = (long long)gridDim.x * blockDim.x;
    for (long long g = tail + (long long)blockIdx.x * blockDim.x + t; g < n4; g += stride)
        out[g] = in[g];
}

extern "C" void kernel_launch(void* const* d_in, const int* in_sizes, int n_in,
                              void* d_out, int out_size, void* d_ws, size_t ws_size,
                              hipStream_t stream) {
    const float* x = (const float*)d_in[0];
    float* out = (float*)d_out;
    long long n4 = (long long)in_sizes[0] / 4;   // 31,457,280 granules
    long long n_steps = n4 >> 10;                // 30,720
    int blocks = 2048;
    long long steps_pb = (n_steps + blocks - 1) / blocks;  // 15 exactly

    smooth_copy<<<blocks, 256, 0, stream>>>((const f4*)x, (f4*)out, n4, steps_pb, x);
}